// Round 1
// baseline (1945.777 us; speedup 1.0000x reference)
//
#include <hip/hip_runtime.h>
#include <math.h>

#define D 4096
#define B 64
#define V 32000
#define TOPK 50
#define MINKEEP 5
#define VPW 32          // vocab rows per wave in GEMM
#define NBINS 8192      // 13-bit radix histogram
#define CAND 2048

// ---------------- LayerNorm: one block per batch row ----------------
__global__ __launch_bounds__(256) void ln_kernel(const float* __restrict__ h,
                                                 const float* __restrict__ lnw,
                                                 const float* __restrict__ lnb,
                                                 float* __restrict__ xn) {
  const int b = blockIdx.x;
  const int tid = threadIdx.x;
  const float4* row = (const float4*)(h + b * D);
  float4 vals[4];
  float s = 0.f, ss = 0.f;
#pragma unroll
  for (int i = 0; i < 4; i++) {
    float4 v = row[tid + i * 256];
    vals[i] = v;
    s += v.x + v.y + v.z + v.w;
    ss += v.x * v.x + v.y * v.y + v.z * v.z + v.w * v.w;
  }
  // wave reduce
#pragma unroll
  for (int off = 32; off; off >>= 1) {
    s += __shfl_xor(s, off, 64);
    ss += __shfl_xor(ss, off, 64);
  }
  __shared__ float as_[4], ass_[4];
  if ((tid & 63) == 0) { as_[tid >> 6] = s; ass_[tid >> 6] = ss; }
  __syncthreads();
  s = as_[0] + as_[1] + as_[2] + as_[3];
  ss = ass_[0] + ass_[1] + ass_[2] + ass_[3];
  const float mean = s / (float)D;
  const float var = ss / (float)D - mean * mean;
  const float inv = rsqrtf(var + 1e-5f);
  const float4* w4 = (const float4*)lnw;
  const float4* b4 = (const float4*)lnb;
  float4* o = (float4*)(xn + b * D);
#pragma unroll
  for (int i = 0; i < 4; i++) {
    int idx = tid + i * 256;
    float4 v = vals[i];
    float4 wv = w4[idx];
    float4 bv = b4[idx];
    float4 r;
    r.x = (v.x - mean) * inv * wv.x + bv.x;
    r.y = (v.y - mean) * inv * wv.y + bv.y;
    r.z = (v.z - mean) * inv * wv.z + bv.z;
    r.w = (v.w - mean) * inv * wv.w + bv.w;
    o[idx] = r;
  }
}

// ---------------- GEMM: logitsT[v][b] = sum_k xn[b][k] * lm_w[v][k] ----------------
// Block = 256 threads = 4 waves. lane = batch row. Each wave: 32 vocab rows,
// one K-quarter (split-K), weights via wave-uniform (scalar) loads.
__global__ __launch_bounds__(256) void gemm_kernel(const float* __restrict__ xn,
                                                   const float* __restrict__ lm_w,
                                                   float* __restrict__ logitsT) {
  const int tid = threadIdx.x;
  const int lane = tid & 63;
  const int wvu = __builtin_amdgcn_readfirstlane(tid >> 6);  // force SGPR: wave id
  const int v0 = blockIdx.x * VPW;
  const int k0 = wvu * (D / 4);  // this wave's K-quarter start (elements)

  float acc[VPW];
#pragma unroll
  for (int i = 0; i < VPW; i++) acc[i] = 0.f;

  const float4* xrow4 = (const float4*)(xn + lane * D + k0);

  for (int kk4 = 0; kk4 < D / 16; kk4++) {  // 256 iters of 4 floats
    float4 xv = xrow4[kk4];
#pragma unroll
    for (int v = 0; v < VPW; v++) {
      const float4 wv4 = *(const float4*)(lm_w + (v0 + v) * D + k0 + kk4 * 4);
      acc[v] = fmaf(xv.x, wv4.x, acc[v]);
      acc[v] = fmaf(xv.y, wv4.y, acc[v]);
      acc[v] = fmaf(xv.z, wv4.z, acc[v]);
      acc[v] = fmaf(xv.w, wv4.w, acc[v]);
    }
  }

  __shared__ float part[4][VPW][64];  // 32 KB
#pragma unroll
  for (int v = 0; v < VPW; v++) part[wvu][v][lane] = acc[v];
  __syncthreads();
  for (int idx = tid; idx < VPW * 64; idx += 256) {
    int v = idx >> 6, b = idx & 63;
    float sum = part[0][v][b] + part[1][v][b] + part[2][v][b] + part[3][v][b];
    logitsT[(v0 + v) * 64 + b] = sum;
  }
}

// ---------------- Top-k + top-p sampling: one block per batch row ----------------
__device__ __forceinline__ unsigned int f2key(float f) {
  unsigned int u = __float_as_uint(f);
  return (u & 0x80000000u) ? ~u : (u | 0x80000000u);
}
__device__ __forceinline__ float key2f(unsigned int k) {
  unsigned int u = (k & 0x80000000u) ? (k ^ 0x80000000u) : ~k;
  return __uint_as_float(u);
}

__global__ __launch_bounds__(256) void topk_kernel(const float* __restrict__ logitsT,
                                                   const float* __restrict__ top_p,
                                                   const float* __restrict__ temperature,
                                                   float* __restrict__ out) {
  const int b = blockIdx.x;
  const int tid = threadIdx.x;

  __shared__ unsigned int hist[NBINS];      // 32 KB
  __shared__ unsigned int ckey[CAND];       // 8 KB
  __shared__ unsigned int cidx[CAND];       // 8 KB
  __shared__ unsigned int sbuf[256];
  __shared__ unsigned int shT, nCand;
  __shared__ float sVals[TOPK];
  __shared__ unsigned int sToks[TOPK];

  for (int i = tid; i < NBINS; i += 256) hist[i] = 0;
  if (tid == 0) { nCand = 0; }
  __syncthreads();

  // Phase 1: histogram of monotone keys (top 13 bits)
  for (int v = tid; v < V; v += 256) {
    unsigned int key = f2key(logitsT[v * 64 + b]);
    atomicAdd(&hist[key >> 19], 1u);
  }
  __syncthreads();

  // Phase 2: suffix scan to find threshold bin (bin containing the 50th largest)
  unsigned int Ls = 0;
  {
    int base = tid * (NBINS / 256);
#pragma unroll
    for (int j = 0; j < NBINS / 256; j++) Ls += hist[base + j];
  }
  unsigned int val = Ls;
  sbuf[tid] = val;
  __syncthreads();
  for (int off = 1; off < 256; off <<= 1) {
    unsigned int add = (tid + off < 256) ? sbuf[tid + off] : 0u;
    __syncthreads();
    val += add;
    sbuf[tid] = val;
    __syncthreads();
  }
  {
    unsigned int run = val - Ls;  // count of keys in chunks above this one
    int base = tid * (NBINS / 256);
    for (int j = NBINS / 256 - 1; j >= 0; j--) {
      unsigned int c = hist[base + j];
      if (run < TOPK && run + c >= TOPK) { shT = (unsigned int)(base + j); }
      run += c;
    }
  }
  __syncthreads();
  const unsigned int T = shT;

  // Phase 3: collect candidates (all values with bin >= T)
  for (int v = tid; v < V; v += 256) {
    unsigned int key = f2key(logitsT[v * 64 + b]);
    if ((key >> 19) >= T) {
      unsigned int pos = atomicAdd(&nCand, 1u);
      if (pos < CAND) { ckey[pos] = key; cidx[pos] = (unsigned int)v; }
    }
  }
  __syncthreads();
  const int M = (int)min(nCand, (unsigned int)CAND);

  // Phase 4: exact rank of each candidate (descending key, ties -> lower idx)
  for (int e = tid; e < M; e += 256) {
    unsigned int ke = ckey[e], ie = cidx[e];
    int rank = 0;
    for (int q = 0; q < M; q++) {
      unsigned int kq = ckey[q];
      rank += (kq > ke) || (kq == ke && cidx[q] < ie);
    }
    if (rank < TOPK) { sVals[rank] = key2f(ke); sToks[rank] = ie; }
  }
  __syncthreads();

  // Phase 5: temperature, softmax, cumsum, top-p mask, final softmax (wave 0)
  if (tid < 64) {
    int j = tid;
    bool act = j < TOPK;
    float temp = temperature[0];
    float pp = top_p[0];
    float lt = act ? (sVals[j] / temp) : -INFINITY;
    float m = lt;
#pragma unroll
    for (int off = 32; off; off >>= 1) m = fmaxf(m, __shfl_xor(m, off, 64));
    float e = act ? expf(lt - m) : 0.f;
    float ssum = e;
#pragma unroll
    for (int off = 32; off; off >>= 1) ssum += __shfl_xor(ssum, off, 64);
    float p = e / ssum;
    float cum = p;
#pragma unroll
    for (int off = 1; off < 64; off <<= 1) {
      float u = __shfl_up(cum, off, 64);
      if (j >= off) cum += u;
    }
    bool keep = (cum < pp) || (j < MINKEEP);
    float fl = act ? (keep ? lt : -1000.0f) : -INFINITY;
    float m2 = fl;
#pragma unroll
    for (int off = 32; off; off >>= 1) m2 = fmaxf(m2, __shfl_xor(m2, off, 64));
    float e2 = act ? expf(fl - m2) : 0.f;
    float s2 = e2;
#pragma unroll
    for (int off = 32; off; off >>= 1) s2 += __shfl_xor(s2, off, 64);
    float p2 = e2 / s2;
    if (act) {
      out[b * TOPK + j] = p2;
      out[B * TOPK + b * TOPK + j] = (float)sToks[j];
    }
  }
}

extern "C" void kernel_launch(void* const* d_in, const int* in_sizes, int n_in,
                              void* d_out, int out_size, void* d_ws, size_t ws_size,
                              hipStream_t stream) {
  const float* h   = (const float*)d_in[0];
  const float* lnw = (const float*)d_in[1];
  const float* lnb = (const float*)d_in[2];
  const float* lmw = (const float*)d_in[3];
  const float* tp  = (const float*)d_in[4];
  const float* tm  = (const float*)d_in[5];
  float* out = (float*)d_out;

  float* xn = (float*)d_ws;            // 64*4096 f32 = 1 MB
  float* logitsT = xn + B * D;         // 32000*64 f32 = 8.2 MB

  ln_kernel<<<B, 256, 0, stream>>>(h, lnw, lnb, xn);
  gemm_kernel<<<V / VPW, 256, 0, stream>>>(xn, lmw, logitsT);
  topk_kernel<<<B, 256, 0, stream>>>(logitsT, tp, tm, out);
}

// Round 2
// 785.025 us; speedup vs baseline: 2.4786x; 2.4786x over previous
//
#include <hip/hip_runtime.h>
#include <math.h>

#define D 4096
#define B 64
#define V 32000
#define TOPK 50
#define MINKEEP 5
#define NBINS 8192
#define CAND 2048

typedef __bf16 bf16x8 __attribute__((ext_vector_type(8)));
typedef unsigned short ushort8v __attribute__((ext_vector_type(8)));
typedef unsigned short ushort4v __attribute__((ext_vector_type(4)));
typedef float f32x4 __attribute__((ext_vector_type(4)));

union U8 { ushort8v u; bf16x8 b; };

// ---------------- LayerNorm + bf16 hi/lo split, MFMA-fragment-swizzled output ----
// A_swz layout: frag index f = (t*128 + s)*64 + laneA, each frag = 8 bf16 (16 B),
// where t = m>>4 (M-tile), s = k>>5 (K-step), laneA = (m&15) + ((k>>3)&3)*16, j = k&7.
__global__ __launch_bounds__(256) void ln_kernel(const float* __restrict__ h,
                                                 const float* __restrict__ lnw,
                                                 const float* __restrict__ lnb,
                                                 unsigned short* __restrict__ Ah,
                                                 unsigned short* __restrict__ Al) {
  const int b = blockIdx.x;
  const int tid = threadIdx.x;
  const float4* row = (const float4*)(h + b * D);
  float4 vals[4];
  float s = 0.f, ss = 0.f;
#pragma unroll
  for (int i = 0; i < 4; i++) {
    float4 v = row[tid + i * 256];
    vals[i] = v;
    s += v.x + v.y + v.z + v.w;
    ss += v.x * v.x + v.y * v.y + v.z * v.z + v.w * v.w;
  }
#pragma unroll
  for (int off = 32; off; off >>= 1) {
    s += __shfl_xor(s, off, 64);
    ss += __shfl_xor(ss, off, 64);
  }
  __shared__ float as_[4], ass_[4];
  if ((tid & 63) == 0) { as_[tid >> 6] = s; ass_[tid >> 6] = ss; }
  __syncthreads();
  s = as_[0] + as_[1] + as_[2] + as_[3];
  ss = ass_[0] + ass_[1] + ass_[2] + ass_[3];
  const float mean = s / (float)D;
  const float var = ss / (float)D - mean * mean;
  const float inv = rsqrtf(var + 1e-5f);
  const float4* w4 = (const float4*)lnw;
  const float4* b4 = (const float4*)lnb;
  const int t = b >> 4, mr = b & 15;
#pragma unroll
  for (int i = 0; i < 4; i++) {
    int q = tid + i * 256;            // float4 index within row; elements 4q..4q+3
    float4 v = vals[i];
    float4 wv = w4[q];
    float4 bv = b4[q];
    float r[4];
    r[0] = (v.x - mean) * inv * wv.x + bv.x;
    r[1] = (v.y - mean) * inv * wv.y + bv.y;
    r[2] = (v.z - mean) * inv * wv.z + bv.z;
    r[3] = (v.w - mean) * inv * wv.w + bv.w;
    int s_ = q >> 3;                  // K-step
    int o = (q >> 1) & 3;             // k-octet
    int laneA = mr + o * 16;
    int jb = (q & 1) * 4;
    long base = ((long)((t * 128 + s_) * 64 + laneA)) * 8 + jb;
    ushort4v hv, lv;
#pragma unroll
    for (int c = 0; c < 4; c++) {
      unsigned u = __float_as_uint(r[c]);
      hv[c] = (unsigned short)(u >> 16);                       // trunc hi
      float hif = __uint_as_float(u & 0xffff0000u);
      lv[c] = (unsigned short)(__float_as_uint(r[c] - hif) >> 16);  // trunc lo
    }
    *(ushort4v*)(Ah + base) = hv;
    *(ushort4v*)(Al + base) = lv;
  }
}

// ---------------- GEMM: logits[b][v] = sum_k x[b][k] * lm_w[v][k] ---------------
// Wave = 16 vocab cols x 64 batch (4 M-tiles of 16x16x32 bf16 MFMA), 3 split passes.
// No LDS, no barriers. Weights stream dense from HBM; A-frags from L2.
__global__ __launch_bounds__(256) void gemm_kernel(const unsigned short* __restrict__ Ah,
                                                   const unsigned short* __restrict__ Al,
                                                   const float* __restrict__ lm_w,
                                                   float* __restrict__ logits) {
  const int tid = threadIdx.x;
  const int lane = tid & 63;
  const int wv = tid >> 6;
  const int n0 = blockIdx.x * 64 + wv * 16;
  const int nl = n0 + (lane & 15);       // this lane's vocab row
  const int ko = (lane >> 4) * 8;        // k-octet within each 32-wide K-step

  const ushort8v* Ah8 = (const ushort8v*)Ah;
  const ushort8v* Al8 = (const ushort8v*)Al;

  f32x4 acc[4] = {};

  const float* wrow = lm_w + (long)nl * D + ko;

  float4 b0 = *(const float4*)(wrow);
  float4 b1 = *(const float4*)(wrow + 4);

  for (int s = 0; s < 128; s++) {
    // prefetch next K-step's weights (wraps harmlessly on last iter)
    const float* p = wrow + ((s + 1) & 127) * 32;
    float4 nb0 = *(const float4*)p;
    float4 nb1 = *(const float4*)(p + 4);

    // A fragments (L2-resident, fragment-order coalesced)
    U8 ah[4], al[4];
#pragma unroll
    for (int t = 0; t < 4; t++) {
      ah[t].u = Ah8[(t * 128 + s) * 64 + lane];
      al[t].u = Al8[(t * 128 + s) * 64 + lane];
    }

    // split-convert B: w = hi + lo (both truncated bf16)
    U8 bh, bl;
    float w8[8] = {b0.x, b0.y, b0.z, b0.w, b1.x, b1.y, b1.z, b1.w};
#pragma unroll
    for (int i = 0; i < 8; i++) {
      unsigned u = __float_as_uint(w8[i]);
      bh.u[i] = (unsigned short)(u >> 16);
      float hif = __uint_as_float(u & 0xffff0000u);
      bl.u[i] = (unsigned short)(__float_as_uint(w8[i] - hif) >> 16);
    }

#pragma unroll
    for (int t = 0; t < 4; t++) {
      acc[t] = __builtin_amdgcn_mfma_f32_16x16x32_bf16(ah[t].b, bh.b, acc[t], 0, 0, 0);
      acc[t] = __builtin_amdgcn_mfma_f32_16x16x32_bf16(ah[t].b, bl.b, acc[t], 0, 0, 0);
      acc[t] = __builtin_amdgcn_mfma_f32_16x16x32_bf16(al[t].b, bh.b, acc[t], 0, 0, 0);
    }
    b0 = nb0;
    b1 = nb1;
  }

  // epilogue: C layout col=lane&15 (n), row=(lane>>4)*4+reg (m within tile)
  const int n = n0 + (lane & 15);
  const int mrow = (lane >> 4) * 4;
#pragma unroll
  for (int t = 0; t < 4; t++) {
#pragma unroll
    for (int r = 0; r < 4; r++) {
      int m = t * 16 + mrow + r;
      logits[(long)m * V + n] = acc[t][r];
    }
  }
}

// ---------------- Top-k + top-p sampling: one block per batch row ----------------
__device__ __forceinline__ unsigned int f2key(float f) {
  unsigned int u = __float_as_uint(f);
  return (u & 0x80000000u) ? ~u : (u | 0x80000000u);
}
__device__ __forceinline__ float key2f(unsigned int k) {
  unsigned int u = (k & 0x80000000u) ? (k ^ 0x80000000u) : ~k;
  return __uint_as_float(u);
}

__global__ __launch_bounds__(256) void topk_kernel(const float* __restrict__ logits,
                                                   const float* __restrict__ top_p,
                                                   const float* __restrict__ temperature,
                                                   float* __restrict__ out) {
  const int b = blockIdx.x;
  const int tid = threadIdx.x;

  __shared__ unsigned int hist[NBINS];
  __shared__ unsigned int ckey[CAND];
  __shared__ unsigned int cidx[CAND];
  __shared__ unsigned int sbuf[256];
  __shared__ unsigned int shT, nCand;
  __shared__ float sVals[TOPK];
  __shared__ unsigned int sToks[TOPK];

  for (int i = tid; i < NBINS; i += 256) hist[i] = 0;
  if (tid == 0) { nCand = 0; }
  __syncthreads();

  // Phase 1: histogram of monotone keys (top 13 bits) — coalesced row read
  const float* lrow = logits + (long)b * V;
  for (int v = tid; v < V; v += 256) {
    unsigned int key = f2key(lrow[v]);
    atomicAdd(&hist[key >> 19], 1u);
  }
  __syncthreads();

  // Phase 2: suffix scan to find threshold bin
  unsigned int Ls = 0;
  {
    int base = tid * (NBINS / 256);
#pragma unroll
    for (int j = 0; j < NBINS / 256; j++) Ls += hist[base + j];
  }
  unsigned int val = Ls;
  sbuf[tid] = val;
  __syncthreads();
  for (int off = 1; off < 256; off <<= 1) {
    unsigned int add = (tid + off < 256) ? sbuf[tid + off] : 0u;
    __syncthreads();
    val += add;
    sbuf[tid] = val;
    __syncthreads();
  }
  {
    unsigned int run = val - Ls;
    int base = tid * (NBINS / 256);
    for (int j = NBINS / 256 - 1; j >= 0; j--) {
      unsigned int c = hist[base + j];
      if (run < TOPK && run + c >= TOPK) { shT = (unsigned int)(base + j); }
      run += c;
    }
  }
  __syncthreads();
  const unsigned int T = shT;

  // Phase 3: collect candidates (all values with bin >= T)
  for (int v = tid; v < V; v += 256) {
    unsigned int key = f2key(lrow[v]);
    if ((key >> 19) >= T) {
      unsigned int pos = atomicAdd(&nCand, 1u);
      if (pos < CAND) { ckey[pos] = key; cidx[pos] = (unsigned int)v; }
    }
  }
  __syncthreads();
  const int M = (int)min(nCand, (unsigned int)CAND);

  // Phase 4: exact rank (descending key, ties -> lower idx)
  for (int e = tid; e < M; e += 256) {
    unsigned int ke = ckey[e], ie = cidx[e];
    int rank = 0;
    for (int q = 0; q < M; q++) {
      unsigned int kq = ckey[q];
      rank += (kq > ke) || (kq == ke && cidx[q] < ie);
    }
    if (rank < TOPK) { sVals[rank] = key2f(ke); sToks[rank] = ie; }
  }
  __syncthreads();

  // Phase 5: temperature, softmax, cumsum, top-p mask, final softmax (wave 0)
  if (tid < 64) {
    int j = tid;
    bool act = j < TOPK;
    float temp = temperature[0];
    float pp = top_p[0];
    float lt = act ? (sVals[j] / temp) : -INFINITY;
    float m = lt;
#pragma unroll
    for (int off = 32; off; off >>= 1) m = fmaxf(m, __shfl_xor(m, off, 64));
    float e = act ? expf(lt - m) : 0.f;
    float ssum = e;
#pragma unroll
    for (int off = 32; off; off >>= 1) ssum += __shfl_xor(ssum, off, 64);
    float p = e / ssum;
    float cum = p;
#pragma unroll
    for (int off = 1; off < 64; off <<= 1) {
      float u = __shfl_up(cum, off, 64);
      if (j >= off) cum += u;
    }
    bool keep = (cum < pp) || (j < MINKEEP);
    float fl = act ? (keep ? lt : -1000.0f) : -INFINITY;
    float m2 = fl;
#pragma unroll
    for (int off = 32; off; off >>= 1) m2 = fmaxf(m2, __shfl_xor(m2, off, 64));
    float e2 = act ? expf(fl - m2) : 0.f;
    float s2 = e2;
#pragma unroll
    for (int off = 32; off; off >>= 1) s2 += __shfl_xor(s2, off, 64);
    float p2 = e2 / s2;
    if (act) {
      out[b * TOPK + j] = p2;
      out[B * TOPK + b * TOPK + j] = (float)sToks[j];
    }
  }
}

extern "C" void kernel_launch(void* const* d_in, const int* in_sizes, int n_in,
                              void* d_out, int out_size, void* d_ws, size_t ws_size,
                              hipStream_t stream) {
  const float* h   = (const float*)d_in[0];
  const float* lnw = (const float*)d_in[1];
  const float* lnb = (const float*)d_in[2];
  const float* lmw = (const float*)d_in[3];
  const float* tp  = (const float*)d_in[4];
  const float* tm  = (const float*)d_in[5];
  float* out = (float*)d_out;

  unsigned short* Ah = (unsigned short*)d_ws;      // 64*4096 bf16 = 512 KB
  unsigned short* Al = Ah + B * D;                 // 512 KB
  float* logits = (float*)(Al + B * D);            // 64*32000 f32 = 8.2 MB

  ln_kernel<<<B, 256, 0, stream>>>(h, lnw, lnb, Ah, Al);
  gemm_kernel<<<V / 64, 256, 0, stream>>>(Ah, Al, lmw, logits);
  topk_kernel<<<B, 256, 0, stream>>>(logits, tp, tm, out);
}